// Round 16
// baseline (97.612 us; speedup 1.0000x reference)
//
#include <hip/hip_runtime.h>
#include <hip/hip_bf16.h>
#include <math.h>

// Problem dims (fixed by reference)
#define B   32
#define P   196      // hw tokens (14x14)
#define C   768
#define NC  4096
#define HH  14
#define KSPLIT 24    // 768 / 32
#define NT  12       // K tiles per GEMM (768 / 64)
#define M6  6272     // B*P
// Packed k-tiled layout: X[kb][row][k'] (kb = k>>5, k' = k&31).  A (kb,
// 128-row) slab is 128*32*2B = 8 KB contiguous -> global_load_lds staging
// is fully coalesced (lane l reads base + l*16B within 1 KB chunks).
#define TW  (768 * 32)    // Wt packed kb stride (elements)
#define TM  (M6 * 32)     // Tok/hdn packed kb stride (elements)

typedef _Float16 half8 __attribute__((ext_vector_type(8)));
typedef _Float16 half4 __attribute__((ext_vector_type(4)));
typedef float f32x4 __attribute__((ext_vector_type(4)));

#define GLOAD_LDS16(g, l)                                                      \
    __builtin_amdgcn_global_load_lds(                                          \
        (const __attribute__((address_space(1))) void*)(g),                    \
        (__attribute__((address_space(3))) void*)(l), 16, 0, 0)

// ---------------------------------------------------------------------------
// K1: SpaceSelfAware + space_fusion + residual.  16-channel blocks.
// ---------------------------------------------------------------------------
__global__ __launch_bounds__(256) void k_ssa(const float* __restrict__ t,
                                             float* __restrict__ pre) {
    const int b = blockIdx.y, c0 = blockIdx.x * 16;
    __shared__ float xp_[256 * 16];        // [(i+2)*16 + (j+1)][cc]  16 KB
    __shared__ float part[4][9][16];
    __shared__ float inv_norm[9][16];
    const int tid = threadIdx.x;
    const int cc = tid & 15, g = tid >> 4, wv = tid >> 6;

#pragma unroll
    for (int q = 0; q < 16; ++q) xp_[q * 256 + tid] = 0.0f;
    __syncthreads();

    for (int idx = tid; idx < 784; idx += 256) {
        const int p = idx >> 2, c = (idx & 3) * 4;
        const int i = p / HH, j = p % HH;
        *(float4*)&xp_[((i + 2) * 16 + (j + 1)) * 16 + c] =
            *(const float4*)&t[((size_t)b * P + p) * C + c0 + c];
    }
    __syncthreads();

    float s[9] = {};
    {
        int i = 0, j = g;
        if (j >= HH) { j -= HH; i = 1; }
        for (int p = g; p < P; p += 16) {
            const int base = ((i + 2) * 16 + (j + 1)) * 16 + cc;
            const float xp = xp_[base];
            const float xp2 = xp * xp;
#pragma unroll
            for (int k = 0; k < 9; ++k) {
                const int off = ((k / 3) - 2) * 16 + (k % 3) - 1;  // const
                const float nb = xp_[base + off * 16];
                s[k] += xp2 * nb * nb;
            }
            j += 2; ++i;
            if (j >= HH) { j -= HH; ++i; }
        }
    }
#pragma unroll
    for (int k = 0; k < 9; ++k) {
        float r = s[k];
        r += __shfl_xor(r, 16);
        r += __shfl_xor(r, 32);
        s[k] = r;
    }
    if ((tid & 63) < 16) {
#pragma unroll
        for (int k = 0; k < 9; ++k) part[wv][k][cc] = s[k];
    }
    __syncthreads();
    if (tid < 144) {
        const int k = tid >> 4, c2 = tid & 15;
        const float t4 = part[0][k][c2] + part[1][k][c2] +
                         part[2][k][c2] + part[3][k][c2];
        inv_norm[k][c2] = 1.0f / fmaxf(sqrtf(t4), 1e-12f);
    }
    __syncthreads();

    float invn[9];
#pragma unroll
    for (int k = 0; k < 9; ++k) invn[k] = inv_norm[k][cc];

    {
        int i = 0, j = g;
        if (j >= HH) { j -= HH; i = 1; }
        for (int p = g; p < P; p += 16) {
            const int base = ((i + 2) * 16 + (j + 1)) * 16 + cc;
            const float xp = xp_[base];
            float acc = 0.0f;
#pragma unroll
            for (int k = 0; k < 9; ++k) {
                const int off = ((k / 3) - 2) * 16 + (k % 3) - 1;
                const float v = xp * xp_[base + off * 16];
                const float u = fmaxf(v * invn[k], 1e-6f);
                acc += u * u * u;
            }
            pre[((size_t)b * P + p) * C + c0 + cc] =
                cbrtf(acc * (1.0f / 9.0f)) + xp;
            j += 2; ++i;
            if (j >= HH) { j -= HH; ++i; }
        }
    }
}

// ---------------------------------------------------------------------------
// K2: L2 normalize each (b,p) row; write f16 tokens in packed layout.
// ---------------------------------------------------------------------------
__global__ __launch_bounds__(256) void k_rownorm(const float* __restrict__ in,
                                                 _Float16* __restrict__ outP) {
    const int row = blockIdx.x;               // b*P + p
    const float* r = in + (size_t)row * C;
    const int tid = threadIdx.x;
    float vals[3];
    float s = 0.0f;
#pragma unroll
    for (int q = 0; q < 3; ++q) {
        vals[q] = r[tid + q * 256];
        s += vals[q] * vals[q];
    }
    __shared__ float partial[4];
    __shared__ float inv;
    __shared__ _Float16 nrm[C];
#pragma unroll
    for (int off = 32; off > 0; off >>= 1) s += __shfl_xor(s, off);
    if ((tid & 63) == 0) partial[tid >> 6] = s;
    __syncthreads();
    if (tid == 0)
        inv = 1.0f / fmaxf(sqrtf(partial[0] + partial[1] + partial[2] + partial[3]), 1e-12f);
    __syncthreads();
#pragma unroll
    for (int q = 0; q < 3; ++q)
        nrm[tid + q * 256] = (_Float16)(vals[q] * inv);
    __syncthreads();
    if (tid < 96) {
        const half8 v = *(const half8*)&nrm[tid * 8];
        const int kb = tid >> 2;                 // c = tid*8, kb = c>>5
        *(half8*)&outP[(size_t)kb * TM + (size_t)row * 32 + (tid & 3) * 8] = v;
    }
}

// ---------------------------------------------------------------------------
// K2b: weight pack: W (K x N) f32 -> WtP packed [kb][n][32] f16
// ---------------------------------------------------------------------------
__global__ __launch_bounds__(256) void k_wt(const float* __restrict__ W,
                                            _Float16* __restrict__ WtP) {
    __shared__ float tt[32][33];
    const int k0 = blockIdx.x * 32, n0 = blockIdx.y * 32;   // kb = blockIdx.x
    const int r = threadIdx.x / 32, c = threadIdx.x % 32;
#pragma unroll
    for (int q = 0; q < 4; ++q)
        tt[r + q * 8][c] = W[(size_t)(k0 + r + q * 8) * C + n0 + c];
    __syncthreads();
    const int nl = threadIdx.x >> 3, h = threadIdx.x & 7;
    const int n = n0 + nl;
    half4 v;
#pragma unroll
    for (int j = 0; j < 4; ++j) v[j] = (_Float16)tt[h * 4 + j][nl];
    *(half4*)&WtP[(size_t)blockIdx.x * TW + (size_t)n * 32 + h * 4] = v;
}

// ---------------------------------------------------------------------------
// K3/K4: f16 MFMA GEMM — 128x128 tile, BK=64, 2-deep counted-vmcnt
// pipeline.  Staged-traffic analysis: 64x64 tiles staged 233 MB through L2
// (measured ~870 cy/iter = the per-CU L2 share); 128x128 halves it to
// 117 MB.  LDS 64 KB (2 stages x 32 KB) -> 2 blocks/CU; grid 294, all
// co-resident.  4 waves (2x2 of 64x64), 32 MFMA/wave per K-step; staging =
// 8 x 1 KB gload_lds per wave per stage, steady wait vmcnt(8).
// Packed operands keep staging fully coalesced + LDS reads conflict-free
// (measured 0 since R11).  XCD swizzle: one m-row's 6 n-tiles per XCD
// (Tok slice 1.2 MB + Wt 1.2 MB fit per-XCD L2).
// GELU=true: output hdn packed f16.  GELU=false: f16 row-major.
// ---------------------------------------------------------------------------
template <bool GELU>
__global__ __launch_bounds__(256) void k_mfma_gemm(
    const _Float16* __restrict__ TokP,  // packed (24 x M6 x 32)  B-operand
    const _Float16* __restrict__ WtP,   // packed (24 x 768 x 32) A-operand
    const float* __restrict__ bias,     // (N)
    _Float16* __restrict__ Cout) {      // packed f16 (GELU) or f16 row-major
    __shared__ _Float16 lA[2][2][128][32];  // [stage][kb][n][k']  32 KB
    __shared__ _Float16 lB[2][2][128][32];  // [stage][kb][m][k']  32 KB
    const int tid = threadIdx.x;
    const int w = tid >> 6, l = tid & 63;
    const int l15 = l & 15, lk = l >> 4;

    // XCD swizzle: equal lid%8 (one XCD) covers one m-row's 6 n-tiles.
    const int lid = blockIdx.x;
    int vm, vn;
    if (lid < 288) { vm = (lid / 48) * 8 + (lid & 7); vn = (lid % 48) >> 3; }
    else           { vm = 48; vn = lid - 288; }
    const int m0 = vm * 128, n0 = vn * 128;
    const int wn = (w & 1) * 64, wm = (w >> 1) * 64;

    f32x4 acc[4][4] = {};   // [fa over n][fb over m]

    // staging: 32 x 1 KB loads/stage; wave w takes gc = w*8 + q.
    // gc 0..15 -> A (kb = gc>>3 & 1), gc 16..31 -> B; ld = gc&7 selects the
    // 16-row slice.  All sources are contiguous 1 KB, lane l at +l*16B.
#define ISSUE(tt, st_)                                                         \
    {                                                                          \
        _Pragma("unroll")                                                      \
        for (int q = 0; q < 8; ++q) {                                          \
            const int gc = w * 8 + q;                                          \
            const bool isA = gc < 16;                                          \
            const int kbp = (gc >> 3) & 1, ld = gc & 7;                        \
            const _Float16* s_ = isA                                           \
                ? WtP + (size_t)(2 * (tt) + kbp) * TW + (size_t)n0 * 32 + ld * 512 \
                : TokP + (size_t)(2 * (tt) + kbp) * TM + (size_t)m0 * 32 + ld * 512; \
            _Float16* d_ = isA ? &lA[st_][kbp][ld * 16][0]                     \
                               : &lB[st_][kbp][ld * 16][0];                    \
            GLOAD_LDS16(s_ + l * 8, d_ + l * 8);                               \
        }                                                                      \
    }

    ISSUE(0, 0); ISSUE(1, 1);   // 16 loads in flight / wave

    for (int t = 0; t < NT; ++t) {
        // own-wave stage-t loads complete; stage t+1 stays in flight
        if (t < NT - 1) asm volatile("s_waitcnt vmcnt(8)" ::: "memory");
        else            asm volatile("s_waitcnt vmcnt(0)" ::: "memory");
        __builtin_amdgcn_s_barrier();          // all waves' stage-t loads done
        __builtin_amdgcn_sched_barrier(0);     // no ds_read hoisted above

        const int st = t & 1;
#pragma unroll
        for (int kk = 0; kk < 2; ++kk) {       // two 32-k sub-steps (kb tiles)
            half8 af[4], bf[4];
#pragma unroll
            for (int fa = 0; fa < 4; ++fa)
                af[fa] = *(const half8*)&lA[st][kk][wn + fa * 16 + l15][lk * 8];
#pragma unroll
            for (int fb = 0; fb < 4; ++fb)
                bf[fb] = *(const half8*)&lB[st][kk][wm + fb * 16 + l15][lk * 8];
#pragma unroll
            for (int fa = 0; fa < 4; ++fa)
#pragma unroll
                for (int fb = 0; fb < 4; ++fb)
                    acc[fa][fb] = __builtin_amdgcn_mfma_f32_16x16x32_f16(
                        af[fa], bf[fb], acc[fa][fb], 0, 0, 0);
        }
        asm volatile("s_waitcnt lgkmcnt(0)" ::: "memory");  // reads retired
        __builtin_amdgcn_s_barrier();          // safe to overwrite stage buf
        __builtin_amdgcn_sched_barrier(0);
        if (t < NT - 2) ISSUE(t + 2, st);      // refill; stays in flight
    }
#undef ISSUE

    // epilogue: lane holds D[n = nb + r][m], r=0..3 consecutive n
#pragma unroll
    for (int fa = 0; fa < 4; ++fa) {
        const int nb = n0 + wn + fa * 16 + lk * 4;
        const float4 bv = *(const float4*)&bias[nb];
#pragma unroll
        for (int fb = 0; fb < 4; ++fb) {
            const int m = m0 + wm + fb * 16 + l15;
            half4 o;
            if (GELU) {
#pragma unroll
                for (int rr = 0; rr < 4; ++rr) {
                    float v = acc[fa][fb][rr] + ((const float*)&bv)[rr];
                    v = 0.5f * v * (1.0f + erff(v * 0.70710678118654752f));
                    o[rr] = (_Float16)v;
                }
                // packed write: hdnP[kb = nb>>5][m][k' = nb&31 .. +3]
                *(half4*)&Cout[(size_t)(nb >> 5) * TM + (size_t)m * 32 +
                               (nb & 31)] = o;
            } else {
#pragma unroll
                for (int rr = 0; rr < 4; ++rr)
                    o[rr] = (_Float16)(acc[fa][fb][rr] + ((const float*)&bv)[rr]);
                *(half4*)&Cout[(size_t)m * C + nb] = o;   // f16 row-major
            }
        }
    }
}

// ---------------------------------------------------------------------------
// K5: GeM over tokens (f16 input): g[b,c] = (mean_p clip(x,1e-6)^3)^(1/3)
// grid (B*12) = 384 blocks; fixed-order 4-group LDS combine.
// ---------------------------------------------------------------------------
__global__ __launch_bounds__(256) void k_gempool(const _Float16* __restrict__ tk,
                                                 float* __restrict__ g) {
    const int b = blockIdx.x / 12;
    const int c0 = (blockIdx.x % 12) * 64;
    const int tid = threadIdx.x;
    const int cc = tid & 63, pg = tid >> 6;
    float s = 0.0f;
    for (int p = pg * 49; p < pg * 49 + 49; ++p) {
        const float v = fmaxf((float)tk[((size_t)b * P + p) * C + c0 + cc], 1e-6f);
        s += v * v * v;
    }
    __shared__ float part[4][64];
    part[pg][cc] = s;
    __syncthreads();
    if (tid < 64) {
        const float t4 = part[0][cc] + part[1][cc] + part[2][cc] + part[3][cc];
        g[b * C + c0 + cc] = cbrtf(t4 * (1.0f / (float)P));
    }
}

// ---------------------------------------------------------------------------
// K6a: head GEMM stage 1 (split-K).  grid (NC/64, KSPLIT) = 1536 blocks.
// ---------------------------------------------------------------------------
__global__ __launch_bounds__(256) void k_head1(const float* __restrict__ g,
                                               const float* __restrict__ W,
                                               float* __restrict__ partial) {
    const int n0 = blockIdx.x * 64;
    const int k0 = blockIdx.y * 32;
    __shared__ float gs[32][32];          // [b][kk]
    __shared__ float part[4][32][64];     // [q][b][c]
    const int tid = threadIdx.x;

    for (int idx = tid; idx < 32 * 32; idx += 256)
        gs[idx >> 5][idx & 31] = g[(idx >> 5) * C + k0 + (idx & 31)];
    __syncthreads();

    const int c = tid & 63, q = tid >> 6;
    float acc[32] = {};
#pragma unroll
    for (int kk = 0; kk < 8; ++kk) {
        const int k = q * 8 + kk;
        const float wv = W[(size_t)(k0 + k) * NC + n0 + c];
#pragma unroll
        for (int b = 0; b < 32; ++b) acc[b] += gs[b][k] * wv;
    }
#pragma unroll
    for (int b = 0; b < 32; ++b) part[q][b][c] = acc[b];
    __syncthreads();

    for (int o = tid; o < 32 * 64; o += 256) {
        const int b = o >> 6, cc = o & 63;
        const float v = part[0][b][cc] + part[1][b][cc] +
                        part[2][b][cc] + part[3][b][cc];
        partial[((size_t)blockIdx.y * 32 + b) * NC + n0 + cc] = v;
    }
}

// ---------------------------------------------------------------------------
// K6b: head GEMM stage 2: fixed-order sum of KSPLIT partials + bias.
// ---------------------------------------------------------------------------
__global__ __launch_bounds__(256) void k_head2(const float* __restrict__ partial,
                                               const float* __restrict__ hb,
                                               float* __restrict__ out) {
    const int n = blockIdx.x * 256 + threadIdx.x;
    const int b = blockIdx.y;
    float s = hb[n];
#pragma unroll
    for (int ks = 0; ks < KSPLIT; ++ks)
        s += partial[((size_t)ks * 32 + b) * NC + n];
    out[(size_t)b * NC + n] = s;
}

// ---------------------------------------------------------------------------
// K7: L2-normalize each batch row of out (4096) in place.
// ---------------------------------------------------------------------------
__global__ __launch_bounds__(256) void k_outnorm(float* __restrict__ out) {
    const int b = blockIdx.x;
    float* r = out + (size_t)b * NC;
    const int tid = threadIdx.x;
    float v[16];
    float s = 0.0f;
#pragma unroll
    for (int q = 0; q < 16; ++q) {
        v[q] = r[tid + q * 256];
        s += v[q] * v[q];
    }
    __shared__ float partial[4];
    __shared__ float inv;
#pragma unroll
    for (int off = 32; off > 0; off >>= 1) s += __shfl_xor(s, off);
    if ((tid & 63) == 0) partial[tid >> 6] = s;
    __syncthreads();
    if (tid == 0)
        inv = 1.0f / fmaxf(sqrtf(partial[0] + partial[1] + partial[2] + partial[3]), 1e-12f);
    __syncthreads();
#pragma unroll
    for (int q = 0; q < 16; ++q) r[tid + q * 256] = v[q] * inv;
}

// ---------------------------------------------------------------------------
extern "C" void kernel_launch(void* const* d_in, const int* in_sizes, int n_in,
                              void* d_out, int out_size, void* d_ws, size_t ws_size,
                              hipStream_t stream) {
    const float* patch  = (const float*)d_in[0];
    const float* fc1_w  = (const float*)d_in[1];
    const float* fc1_b  = (const float*)d_in[2];
    const float* fc2_w  = (const float*)d_in[3];
    const float* fc2_b  = (const float*)d_in[4];
    const float* head_w = (const float*)d_in[5];
    const float* head_b = (const float*)d_in[6];
    float* out = (float*)d_out;

    const size_t big = (size_t)B * P * C;        // 4,816,896 elements
    float*    pre  = (float*)d_ws;               // [big] f32; later reused as tok2
    _Float16* tokP = (_Float16*)(pre + big);     // [big] f16 packed
    _Float16* hdnP = tokP + big;                 // [big] f16 packed
    _Float16* wt1  = hdnP + big;                 // [768*768] f16 packed
    _Float16* wt2  = wt1 + C * C;                // [768*768] f16 packed
    float*    gbuf = (float*)(wt2 + C * C);      // [32*768] f32
    float*    hpart = gbuf + B * C;              // [KSPLIT*32*4096] f32
    _Float16* tok2 = (_Float16*)pre;             // reuse (f16 row-major)

    // K1: SSA + fusion + residual -> pre
    k_ssa<<<dim3(C / 16, B), dim3(256), 0, stream>>>(patch, pre);
    // weight packs (independent)
    k_wt<<<dim3(C / 32, C / 32), dim3(256), 0, stream>>>(fc1_w, wt1);
    k_wt<<<dim3(C / 32, C / 32), dim3(256), 0, stream>>>(fc2_w, wt2);
    // K2: channel L2 norm -> tokP (f16 packed)
    k_rownorm<<<dim3(B * P), dim3(256), 0, stream>>>(pre, tokP);
    // K3: fc1 + gelu -> hdnP (f16 packed)
    k_mfma_gemm<true><<<dim3(294), dim3(256), 0, stream>>>(
        tokP, wt1, fc1_b, hdnP);
    // K4: fc2 -> tok2 (f16 row-major)
    k_mfma_gemm<false><<<dim3(294), dim3(256), 0, stream>>>(
        hdnP, wt2, fc2_b, tok2);
    // K5: GeM over tokens -> gbuf
    k_gempool<<<dim3(B * 12), dim3(256), 0, stream>>>(tok2, gbuf);
    // K6: head GEMM, split-K two-stage -> out (pre-normalized)
    k_head1<<<dim3(NC / 64, KSPLIT), dim3(256), 0, stream>>>(gbuf, head_w, hpart);
    k_head2<<<dim3(NC / 256, B), dim3(256), 0, stream>>>(hpart, head_b, out);
    // K7: normalize rows of out
    k_outnorm<<<dim3(B), dim3(256), 0, stream>>>(out);
}

// Round 17
// 94.027 us; speedup vs baseline: 1.0381x; 1.0381x over previous
//
#include <hip/hip_runtime.h>
#include <hip/hip_bf16.h>
#include <math.h>

// Problem dims (fixed by reference)
#define B   32
#define P   196      // hw tokens (14x14)
#define C   768
#define NC  4096
#define HH  14
#define KSPLIT 24    // 768 / 32
#define NT  12       // K tiles per GEMM (768 / 64)
#define M6  6272     // B*P
// Packed k-tiled layout with T2 bank swizzle:
//   element (row, k) stored at X[kb][row][ k' ^ (((row>>1)&3)<<3) ]
//   (kb = k>>5, k' = k&31).  The XOR permutes 16B slots within each 64 B
//   row, so a wave's ds_read_b128 fragment read (16 consecutive rows x one
//   slot) hits all 8 bank-groups -> 2-way conflict (free) instead of 8-way.
//   Staging via global_load_lds is a LINEAR copy (swizzle pre-baked in the
//   global source, rule #21); reads apply the same XOR.
#define TW  (768 * 32)    // Wt packed kb stride (elements)
#define TM  (M6 * 32)     // Tok/hdn packed kb stride (elements)

typedef _Float16 half8 __attribute__((ext_vector_type(8)));
typedef _Float16 half4 __attribute__((ext_vector_type(4)));
typedef float f32x4 __attribute__((ext_vector_type(4)));

#define GLOAD_LDS16(g, l)                                                      \
    __builtin_amdgcn_global_load_lds(                                          \
        (const __attribute__((address_space(1))) void*)(g),                    \
        (__attribute__((address_space(3))) void*)(l), 16, 0, 0)

// ---------------------------------------------------------------------------
// K1: SpaceSelfAware + space_fusion + residual.  16-channel blocks.
// ---------------------------------------------------------------------------
__global__ __launch_bounds__(256) void k_ssa(const float* __restrict__ t,
                                             float* __restrict__ pre) {
    const int b = blockIdx.y, c0 = blockIdx.x * 16;
    __shared__ float xp_[256 * 16];        // [(i+2)*16 + (j+1)][cc]  16 KB
    __shared__ float part[4][9][16];
    __shared__ float inv_norm[9][16];
    const int tid = threadIdx.x;
    const int cc = tid & 15, g = tid >> 4, wv = tid >> 6;

#pragma unroll
    for (int q = 0; q < 16; ++q) xp_[q * 256 + tid] = 0.0f;
    __syncthreads();

    for (int idx = tid; idx < 784; idx += 256) {
        const int p = idx >> 2, c = (idx & 3) * 4;
        const int i = p / HH, j = p % HH;
        *(float4*)&xp_[((i + 2) * 16 + (j + 1)) * 16 + c] =
            *(const float4*)&t[((size_t)b * P + p) * C + c0 + c];
    }
    __syncthreads();

    float s[9] = {};
    {
        int i = 0, j = g;
        if (j >= HH) { j -= HH; i = 1; }
        for (int p = g; p < P; p += 16) {
            const int base = ((i + 2) * 16 + (j + 1)) * 16 + cc;
            const float xp = xp_[base];
            const float xp2 = xp * xp;
#pragma unroll
            for (int k = 0; k < 9; ++k) {
                const int off = ((k / 3) - 2) * 16 + (k % 3) - 1;  // const
                const float nb = xp_[base + off * 16];
                s[k] += xp2 * nb * nb;
            }
            j += 2; ++i;
            if (j >= HH) { j -= HH; ++i; }
        }
    }
#pragma unroll
    for (int k = 0; k < 9; ++k) {
        float r = s[k];
        r += __shfl_xor(r, 16);
        r += __shfl_xor(r, 32);
        s[k] = r;
    }
    if ((tid & 63) < 16) {
#pragma unroll
        for (int k = 0; k < 9; ++k) part[wv][k][cc] = s[k];
    }
    __syncthreads();
    if (tid < 144) {
        const int k = tid >> 4, c2 = tid & 15;
        const float t4 = part[0][k][c2] + part[1][k][c2] +
                         part[2][k][c2] + part[3][k][c2];
        inv_norm[k][c2] = 1.0f / fmaxf(sqrtf(t4), 1e-12f);
    }
    __syncthreads();

    float invn[9];
#pragma unroll
    for (int k = 0; k < 9; ++k) invn[k] = inv_norm[k][cc];

    {
        int i = 0, j = g;
        if (j >= HH) { j -= HH; i = 1; }
        for (int p = g; p < P; p += 16) {
            const int base = ((i + 2) * 16 + (j + 1)) * 16 + cc;
            const float xp = xp_[base];
            float acc = 0.0f;
#pragma unroll
            for (int k = 0; k < 9; ++k) {
                const int off = ((k / 3) - 2) * 16 + (k % 3) - 1;
                const float v = xp * xp_[base + off * 16];
                const float u = fmaxf(v * invn[k], 1e-6f);
                acc += u * u * u;
            }
            pre[((size_t)b * P + p) * C + c0 + cc] =
                cbrtf(acc * (1.0f / 9.0f)) + xp;
            j += 2; ++i;
            if (j >= HH) { j -= HH; ++i; }
        }
    }
}

// ---------------------------------------------------------------------------
// K2: L2 normalize each (b,p) row; write f16 tokens in packed+swizzled
// layout via LDS bounce (half8 stores; slot = (tid&3) ^ ((row>>1)&3)).
// ---------------------------------------------------------------------------
__global__ __launch_bounds__(256) void k_rownorm(const float* __restrict__ in,
                                                 _Float16* __restrict__ outP) {
    const int row = blockIdx.x;               // b*P + p
    const float* r = in + (size_t)row * C;
    const int tid = threadIdx.x;
    float vals[3];
    float s = 0.0f;
#pragma unroll
    for (int q = 0; q < 3; ++q) {
        vals[q] = r[tid + q * 256];
        s += vals[q] * vals[q];
    }
    __shared__ float partial[4];
    __shared__ float inv;
    __shared__ _Float16 nrm[C];
#pragma unroll
    for (int off = 32; off > 0; off >>= 1) s += __shfl_xor(s, off);
    if ((tid & 63) == 0) partial[tid >> 6] = s;
    __syncthreads();
    if (tid == 0)
        inv = 1.0f / fmaxf(sqrtf(partial[0] + partial[1] + partial[2] + partial[3]), 1e-12f);
    __syncthreads();
#pragma unroll
    for (int q = 0; q < 3; ++q)
        nrm[tid + q * 256] = (_Float16)(vals[q] * inv);
    __syncthreads();
    if (tid < 96) {
        const half8 v = *(const half8*)&nrm[tid * 8];
        const int kb = tid >> 2;                 // c = tid*8, kb = c>>5
        const int slot = (tid & 3) ^ ((row >> 1) & 3);   // T2 swizzle
        *(half8*)&outP[(size_t)kb * TM + (size_t)row * 32 + slot * 8] = v;
    }
}

// ---------------------------------------------------------------------------
// K2b: weight pack: W (K x N) f32 -> WtP packed+swizzled [kb][n][32] f16
// ---------------------------------------------------------------------------
__global__ __launch_bounds__(256) void k_wt(const float* __restrict__ W,
                                            _Float16* __restrict__ WtP) {
    __shared__ float tt[32][33];
    const int k0 = blockIdx.x * 32, n0 = blockIdx.y * 32;   // kb = blockIdx.x
    const int r = threadIdx.x / 32, c = threadIdx.x % 32;
#pragma unroll
    for (int q = 0; q < 4; ++q)
        tt[r + q * 8][c] = W[(size_t)(k0 + r + q * 8) * C + n0 + c];
    __syncthreads();
    const int nl = threadIdx.x >> 3, h = threadIdx.x & 7;
    const int n = n0 + nl;
    half4 v;
#pragma unroll
    for (int j = 0; j < 4; ++j) v[j] = (_Float16)tt[h * 4 + j][nl];
    const int el = (h * 4) ^ (((n >> 1) & 3) << 3);          // T2 swizzle
    *(half4*)&WtP[(size_t)blockIdx.x * TW + (size_t)n * 32 + el] = v;
}

// ---------------------------------------------------------------------------
// K3/K4: f16 MFMA GEMM — R15 measured-best structure (3-deep counted-vmcnt
// pipeline, 64M x 64N, BK=64, grid 1176, XCD swizzle) + T2 bank swizzle on
// fragment reads: col = (lk ^ ((row>>1)&3)) * 8.  8-way -> 2-way (free).
// GELU=true: output hdn packed+swizzled f16.  GELU=false: f16 row-major.
// ---------------------------------------------------------------------------
template <bool GELU>
__global__ __launch_bounds__(256) void k_mfma_gemm(
    const _Float16* __restrict__ TokP,  // packed (24 x M6 x 32)  B-operand
    const _Float16* __restrict__ WtP,   // packed (24 x 768 x 32) A-operand
    const float* __restrict__ bias,     // (N)
    _Float16* __restrict__ Cout) {      // packed f16 (GELU) or f16 row-major
    __shared__ _Float16 lA[3][2][64][32];  // [buf][kb][n][k'']
    __shared__ _Float16 lB[3][2][64][32];  // [buf][kb][m][k'']
    const int tid = threadIdx.x;
    const int w = tid >> 6, l = tid & 63;
    const int l15 = l & 15, lk = l >> 4;

    // XCD swizzle: equal lid%8 (one XCD) covers one m-row's 12 n-tiles.
    const int lid = blockIdx.x;
    int vm, vn;
    if (lid < 1152) { vm = (lid / 96) * 8 + (lid & 7); vn = (lid % 96) >> 3; }
    else            { const int r = lid - 1152; vm = 96 + r / 12; vn = r % 12; }
    const int m0 = vm * 64, n0 = vn * 64;
    const int wn = (w & 1) * 32, wm = (w >> 1) * 32;

    f32x4 acc[2][2] = {};   // [fa over n][fb over m]

    // wave w stages one 4 KB chunk per stage: w<2 -> A (kb = w&1), else B
    const int kbsel = w & 1;
    const bool isB = (w >= 2);
    const _Float16* srcBase =
        isB ? (TokP + (size_t)m0 * 32) : (WtP + (size_t)n0 * 32);
    const size_t tileStride = isB ? (size_t)TM : (size_t)TW;
    _Float16* dst0 = isB ? &lB[0][kbsel][0][0] : &lA[0][kbsel][0][0];

#define ISSUE(tt, bf_)                                                         \
    {   const _Float16* s_ = srcBase + (size_t)(2 * (tt) + kbsel) * tileStride;\
        _Float16* d_ = dst0 + (size_t)(bf_) * 4096;                            \
        GLOAD_LDS16(s_ + l * 8,        d_ + l * 8);                            \
        GLOAD_LDS16(s_ + 512 + l * 8,  d_ + 512 + l * 8);                      \
        GLOAD_LDS16(s_ + 1024 + l * 8, d_ + 1024 + l * 8);                     \
        GLOAD_LDS16(s_ + 1536 + l * 8, d_ + 1536 + l * 8); }

    ISSUE(0, 0); ISSUE(1, 1); ISSUE(2, 2);   // 12 loads in flight / wave

    for (int t = 0; t < NT; ++t) {
        // own-wave tile-t loads complete; t+1, t+2 remain in flight
        if (t < NT - 2)       asm volatile("s_waitcnt vmcnt(8)" ::: "memory");
        else if (t == NT - 2) asm volatile("s_waitcnt vmcnt(4)" ::: "memory");
        else                  asm volatile("s_waitcnt vmcnt(0)" ::: "memory");
        __builtin_amdgcn_s_barrier();          // all waves' tile-t loads done
        __builtin_amdgcn_sched_barrier(0);     // no ds_read hoisted above

        const int buf = t % 3;
#pragma unroll
        for (int kk = 0; kk < 2; ++kk) {       // two 32-k sub-steps (kb tiles)
            half8 af[2], bf[2];
#pragma unroll
            for (int fa = 0; fa < 2; ++fa) {
                const int rowA = wn + fa * 16 + l15;
                const int colA = (lk ^ ((rowA >> 1) & 3)) * 8;   // T2 read
                af[fa] = *(const half8*)&lA[buf][kk][rowA][colA];
            }
#pragma unroll
            for (int fb = 0; fb < 2; ++fb) {
                const int rowB = wm + fb * 16 + l15;
                const int colB = (lk ^ ((rowB >> 1) & 3)) * 8;   // T2 read
                bf[fb] = *(const half8*)&lB[buf][kk][rowB][colB];
            }
#pragma unroll
            for (int fa = 0; fa < 2; ++fa)
#pragma unroll
                for (int fb = 0; fb < 2; ++fb)
                    acc[fa][fb] = __builtin_amdgcn_mfma_f32_16x16x32_f16(
                        af[fa], bf[fb], acc[fa][fb], 0, 0, 0);
        }
        asm volatile("s_waitcnt lgkmcnt(0)" ::: "memory");  // reads retired
        __builtin_amdgcn_s_barrier();          // safe to overwrite buf
        __builtin_amdgcn_sched_barrier(0);
        if (t < NT - 3) ISSUE(t + 3, buf);     // refill; stays in flight
    }
#undef ISSUE

    // epilogue: lane holds D[n = nb + r][m], r=0..3 consecutive n
#pragma unroll
    for (int fa = 0; fa < 2; ++fa) {
        const int nb = n0 + wn + fa * 16 + lk * 4;
        const float4 bv = *(const float4*)&bias[nb];
#pragma unroll
        for (int fb = 0; fb < 2; ++fb) {
            const int m = m0 + wm + fb * 16 + l15;
            half4 o;
            if (GELU) {
#pragma unroll
                for (int rr = 0; rr < 4; ++rr) {
                    float v = acc[fa][fb][rr] + ((const float*)&bv)[rr];
                    v = 0.5f * v * (1.0f + erff(v * 0.70710678118654752f));
                    o[rr] = (_Float16)v;
                }
                // packed+swizzled write: hdnP[kb][m][ (nb&31)^((m>>1&3)<<3) ]
                const int el = (nb & 31) ^ (((m >> 1) & 3) << 3);
                *(half4*)&Cout[(size_t)(nb >> 5) * TM + (size_t)m * 32 + el] = o;
            } else {
#pragma unroll
                for (int rr = 0; rr < 4; ++rr)
                    o[rr] = (_Float16)(acc[fa][fb][rr] + ((const float*)&bv)[rr]);
                *(half4*)&Cout[(size_t)m * C + nb] = o;   // f16 row-major
            }
        }
    }
}

// ---------------------------------------------------------------------------
// K5: GeM over tokens (f16 input): g[b,c] = (mean_p clip(x,1e-6)^3)^(1/3)
// grid (B*12) = 384 blocks; fixed-order 4-group LDS combine.
// ---------------------------------------------------------------------------
__global__ __launch_bounds__(256) void k_gempool(const _Float16* __restrict__ tk,
                                                 float* __restrict__ g) {
    const int b = blockIdx.x / 12;
    const int c0 = (blockIdx.x % 12) * 64;
    const int tid = threadIdx.x;
    const int cc = tid & 63, pg = tid >> 6;
    float s = 0.0f;
    for (int p = pg * 49; p < pg * 49 + 49; ++p) {
        const float v = fmaxf((float)tk[((size_t)b * P + p) * C + c0 + cc], 1e-6f);
        s += v * v * v;
    }
    __shared__ float part[4][64];
    part[pg][cc] = s;
    __syncthreads();
    if (tid < 64) {
        const float t4 = part[0][cc] + part[1][cc] + part[2][cc] + part[3][cc];
        g[b * C + c0 + cc] = cbrtf(t4 * (1.0f / (float)P));
    }
}

// ---------------------------------------------------------------------------
// K6a: head GEMM stage 1 (split-K).  grid (NC/64, KSPLIT) = 1536 blocks.
// ---------------------------------------------------------------------------
__global__ __launch_bounds__(256) void k_head1(const float* __restrict__ g,
                                               const float* __restrict__ W,
                                               float* __restrict__ partial) {
    const int n0 = blockIdx.x * 64;
    const int k0 = blockIdx.y * 32;
    __shared__ float gs[32][32];          // [b][kk]
    __shared__ float part[4][32][64];     // [q][b][c]
    const int tid = threadIdx.x;

    for (int idx = tid; idx < 32 * 32; idx += 256)
        gs[idx >> 5][idx & 31] = g[(idx >> 5) * C + k0 + (idx & 31)];
    __syncthreads();

    const int c = tid & 63, q = tid >> 6;
    float acc[32] = {};
#pragma unroll
    for (int kk = 0; kk < 8; ++kk) {
        const int k = q * 8 + kk;
        const float wv = W[(size_t)(k0 + k) * NC + n0 + c];
#pragma unroll
        for (int b = 0; b < 32; ++b) acc[b] += gs[b][k] * wv;
    }
#pragma unroll
    for (int b = 0; b < 32; ++b) part[q][b][c] = acc[b];
    __syncthreads();

    for (int o = tid; o < 32 * 64; o += 256) {
        const int b = o >> 6, cc = o & 63;
        const float v = part[0][b][cc] + part[1][b][cc] +
                        part[2][b][cc] + part[3][b][cc];
        partial[((size_t)blockIdx.y * 32 + b) * NC + n0 + cc] = v;
    }
}

// ---------------------------------------------------------------------------
// K6b: head GEMM stage 2: fixed-order sum of KSPLIT partials + bias.
// ---------------------------------------------------------------------------
__global__ __launch_bounds__(256) void k_head2(const float* __restrict__ partial,
                                               const float* __restrict__ hb,
                                               float* __restrict__ out) {
    const int n = blockIdx.x * 256 + threadIdx.x;
    const int b = blockIdx.y;
    float s = hb[n];
#pragma unroll
    for (int ks = 0; ks < KSPLIT; ++ks)
        s += partial[((size_t)ks * 32 + b) * NC + n];
    out[(size_t)b * NC + n] = s;
}

// ---------------------------------------------------------------------------
// K7: L2-normalize each batch row of out (4096) in place.
// ---------------------------------------------------------------------------
__global__ __launch_bounds__(256) void k_outnorm(float* __restrict__ out) {
    const int b = blockIdx.x;
    float* r = out + (size_t)b * NC;
    const int tid = threadIdx.x;
    float v[16];
    float s = 0.0f;
#pragma unroll
    for (int q = 0; q < 16; ++q) {
        v[q] = r[tid + q * 256];
        s += v[q] * v[q];
    }
    __shared__ float partial[4];
    __shared__ float inv;
#pragma unroll
    for (int off = 32; off > 0; off >>= 1) s += __shfl_xor(s, off);
    if ((tid & 63) == 0) partial[tid >> 6] = s;
    __syncthreads();
    if (tid == 0)
        inv = 1.0f / fmaxf(sqrtf(partial[0] + partial[1] + partial[2] + partial[3]), 1e-12f);
    __syncthreads();
#pragma unroll
    for (int q = 0; q < 16; ++q) r[tid + q * 256] = v[q] * inv;
}

// ---------------------------------------------------------------------------
extern "C" void kernel_launch(void* const* d_in, const int* in_sizes, int n_in,
                              void* d_out, int out_size, void* d_ws, size_t ws_size,
                              hipStream_t stream) {
    const float* patch  = (const float*)d_in[0];
    const float* fc1_w  = (const float*)d_in[1];
    const float* fc1_b  = (const float*)d_in[2];
    const float* fc2_w  = (const float*)d_in[3];
    const float* fc2_b  = (const float*)d_in[4];
    const float* head_w = (const float*)d_in[5];
    const float* head_b = (const float*)d_in[6];
    float* out = (float*)d_out;

    const size_t big = (size_t)B * P * C;        // 4,816,896 elements
    float*    pre  = (float*)d_ws;               // [big] f32; later reused as tok2
    _Float16* tokP = (_Float16*)(pre + big);     // [big] f16 packed+swz
    _Float16* hdnP = tokP + big;                 // [big] f16 packed+swz
    _Float16* wt1  = hdnP + big;                 // [768*768] f16 packed+swz
    _Float16* wt2  = wt1 + C * C;                // [768*768] f16 packed+swz
    float*    gbuf = (float*)(wt2 + C * C);      // [32*768] f32
    float*    hpart = gbuf + B * C;              // [KSPLIT*32*4096] f32
    _Float16* tok2 = (_Float16*)pre;             // reuse (f16 row-major)

    // K1: SSA + fusion + residual -> pre
    k_ssa<<<dim3(C / 16, B), dim3(256), 0, stream>>>(patch, pre);
    // weight packs (independent)
    k_wt<<<dim3(C / 32, C / 32), dim3(256), 0, stream>>>(fc1_w, wt1);
    k_wt<<<dim3(C / 32, C / 32), dim3(256), 0, stream>>>(fc2_w, wt2);
    // K2: channel L2 norm -> tokP (f16 packed+swz)
    k_rownorm<<<dim3(B * P), dim3(256), 0, stream>>>(pre, tokP);
    // K3: fc1 + gelu -> hdnP (f16 packed+swz)
    k_mfma_gemm<true><<<dim3(1176), dim3(256), 0, stream>>>(
        tokP, wt1, fc1_b, hdnP);
    // K4: fc2 -> tok2 (f16 row-major)
    k_mfma_gemm<false><<<dim3(1176), dim3(256), 0, stream>>>(
        hdnP, wt2, fc2_b, tok2);
    // K5: GeM over tokens -> gbuf
    k_gempool<<<dim3(B * 12), dim3(256), 0, stream>>>(tok2, gbuf);
    // K6: head GEMM, split-K two-stage -> out (pre-normalized)
    k_head1<<<dim3(NC / 64, KSPLIT), dim3(256), 0, stream>>>(gbuf, head_w, hpart);
    k_head2<<<dim3(NC / 256, B), dim3(256), 0, stream>>>(hpart, head_b, out);
    // K7: normalize rows of out
    k_outnorm<<<dim3(B), dim3(256), 0, stream>>>(out);
}

// Round 18
// 93.307 us; speedup vs baseline: 1.0461x; 1.0077x over previous
//
#include <hip/hip_runtime.h>
#include <hip/hip_bf16.h>
#include <math.h>

// Problem dims (fixed by reference)
#define B   32
#define P   196      // hw tokens (14x14)
#define C   768
#define NC  4096
#define HH  14
#define KSPLIT 24    // 768 / 32
#define NT  12       // K tiles per GEMM (768 / 64)
#define M6  6272     // B*P
// Packed k-tiled layout with T2 bank swizzle (R17, measured-best):
//   element (row, k) stored at X[kb][row][ k' ^ (((row>>1)&3)<<3) ]
//   (kb = k>>5, k' = k&31).  Staging is a LINEAR 4 KB copy; LDS fragment
//   reads apply the same XOR -> 2-way bank conflict (free).
#define TW  (768 * 32)    // Wt packed kb stride (elements)
#define TM  (M6 * 32)     // Tok/hdn packed kb stride (elements)

typedef _Float16 half8 __attribute__((ext_vector_type(8)));
typedef _Float16 half4 __attribute__((ext_vector_type(4)));
typedef float f32x4 __attribute__((ext_vector_type(4)));

#define GLOAD_LDS16(g, l)                                                      \
    __builtin_amdgcn_global_load_lds(                                          \
        (const __attribute__((address_space(1))) void*)(g),                    \
        (__attribute__((address_space(3))) void*)(l), 16, 0, 0)

// ---------------------------------------------------------------------------
// K1: SpaceSelfAware + space_fusion + residual + PACK.  16-channel blocks.
// Emits UNNORMALIZED tokens directly in packed+swizzled f16 (the fc1
// B-operand format) + per-(16ch, row) sum-of-squares partials.  The row
// L2-norm is applied inside fc1's epilogue ((x/|x|)@W = (x@W)*inv).
// ---------------------------------------------------------------------------
__global__ __launch_bounds__(256) void k_ssa(const float* __restrict__ t,
                                             _Float16* __restrict__ outP,
                                             float* __restrict__ partial) {
    const int b = blockIdx.y, cb = blockIdx.x, c0 = cb * 16;
    __shared__ float xp_[256 * 16];        // [(i+2)*16 + (j+1)][cc]  16 KB
    __shared__ float part[4][9][16];
    __shared__ float inv_norm[9][16];
    __shared__ _Float16 outT[P][16];       // 6.3 KB
    const int tid = threadIdx.x;
    const int cc = tid & 15, g = tid >> 4, wv = tid >> 6;

#pragma unroll
    for (int q = 0; q < 16; ++q) xp_[q * 256 + tid] = 0.0f;
    __syncthreads();

    for (int idx = tid; idx < 784; idx += 256) {
        const int p = idx >> 2, c = (idx & 3) * 4;
        const int i = p / HH, j = p % HH;
        *(float4*)&xp_[((i + 2) * 16 + (j + 1)) * 16 + c] =
            *(const float4*)&t[((size_t)b * P + p) * C + c0 + c];
    }
    __syncthreads();

    float s[9] = {};
    {
        int i = 0, j = g;
        if (j >= HH) { j -= HH; i = 1; }
        for (int p = g; p < P; p += 16) {
            const int base = ((i + 2) * 16 + (j + 1)) * 16 + cc;
            const float xp = xp_[base];
            const float xp2 = xp * xp;
#pragma unroll
            for (int k = 0; k < 9; ++k) {
                const int off = ((k / 3) - 2) * 16 + (k % 3) - 1;  // const
                const float nb = xp_[base + off * 16];
                s[k] += xp2 * nb * nb;
            }
            j += 2; ++i;
            if (j >= HH) { j -= HH; ++i; }
        }
    }
#pragma unroll
    for (int k = 0; k < 9; ++k) {
        float r = s[k];
        r += __shfl_xor(r, 16);
        r += __shfl_xor(r, 32);
        s[k] = r;
    }
    if ((tid & 63) < 16) {
#pragma unroll
        for (int k = 0; k < 9; ++k) part[wv][k][cc] = s[k];
    }
    __syncthreads();
    if (tid < 144) {
        const int k = tid >> 4, c2 = tid & 15;
        const float t4 = part[0][k][c2] + part[1][k][c2] +
                         part[2][k][c2] + part[3][k][c2];
        inv_norm[k][c2] = 1.0f / fmaxf(sqrtf(t4), 1e-12f);
    }
    __syncthreads();

    float invn[9];
#pragma unroll
    for (int k = 0; k < 9; ++k) invn[k] = inv_norm[k][cc];

    {
        int i = 0, j = g;
        if (j >= HH) { j -= HH; i = 1; }
        for (int p = g; p < P; p += 16) {
            const int base = ((i + 2) * 16 + (j + 1)) * 16 + cc;
            const float xp = xp_[base];
            float acc = 0.0f;
#pragma unroll
            for (int k = 0; k < 9; ++k) {
                const int off = ((k / 3) - 2) * 16 + (k % 3) - 1;
                const float v = xp * xp_[base + off * 16];
                const float u = fmaxf(v * invn[k], 1e-6f);
                acc += u * u * u;
            }
            const float val = cbrtf(acc * (1.0f / 9.0f)) + xp;
            // row sum-of-squares over this block's 16 channels (16-lane tree)
            float rs = val * val;
            rs += __shfl_xor(rs, 1);
            rs += __shfl_xor(rs, 2);
            rs += __shfl_xor(rs, 4);
            rs += __shfl_xor(rs, 8);
            outT[p][cc] = (_Float16)val;
            if (cc == 0) partial[(size_t)cb * M6 + b * P + p] = rs;
            j += 2; ++i;
            if (j >= HH) { j -= HH; ++i; }
        }
    }
    __syncthreads();
    // pack: 392 half8 stores into tokU[kb][row][swizzled slot]
    const int kb = cb >> 1, kbase = (cb & 1) * 16;
    for (int idx = tid; idx < P * 2; idx += 256) {
        const int p = idx >> 1, h = idx & 1;
        const half8 v = *(const half8*)&outT[p][h * 8];
        const int row = b * P + p;
        const int slot = ((kbase + h * 8) >> 3) ^ ((row >> 1) & 3);   // T2
        *(half8*)&outP[(size_t)kb * TM + (size_t)row * 32 + slot * 8] = v;
    }
}

// ---------------------------------------------------------------------------
// K1b: inv[row] = 1/max(sqrt(sum of 48 partials), eps).  Fixed-order sum.
// ---------------------------------------------------------------------------
__global__ __launch_bounds__(256) void k_inv(const float* __restrict__ partial,
                                             float* __restrict__ inv) {
    const int row = blockIdx.x * 256 + threadIdx.x;
    if (row < M6) {
        float s = 0.0f;
#pragma unroll 8
        for (int cb = 0; cb < 48; ++cb) s += partial[(size_t)cb * M6 + row];
        inv[row] = 1.0f / fmaxf(sqrtf(s), 1e-12f);
    }
}

// ---------------------------------------------------------------------------
// K2b: weight pack: W (K x N) f32 -> WtP packed+swizzled [kb][n][32] f16
// blockIdx.z selects which of the two weight matrices.
// ---------------------------------------------------------------------------
__global__ __launch_bounds__(256) void k_wt(const float* __restrict__ W1,
                                            const float* __restrict__ W2,
                                            _Float16* __restrict__ O1,
                                            _Float16* __restrict__ O2) {
    const float* W = blockIdx.z ? W2 : W1;
    _Float16* WtP = blockIdx.z ? O2 : O1;
    __shared__ float tt[32][33];
    const int k0 = blockIdx.x * 32, n0 = blockIdx.y * 32;   // kb = blockIdx.x
    const int r = threadIdx.x / 32, c = threadIdx.x % 32;
#pragma unroll
    for (int q = 0; q < 4; ++q)
        tt[r + q * 8][c] = W[(size_t)(k0 + r + q * 8) * C + n0 + c];
    __syncthreads();
    const int nl = threadIdx.x >> 3, h = threadIdx.x & 7;
    const int n = n0 + nl;
    half4 v;
#pragma unroll
    for (int j = 0; j < 4; ++j) v[j] = (_Float16)tt[h * 4 + j][nl];
    const int el = (h * 4) ^ (((n >> 1) & 3) << 3);          // T2 swizzle
    *(half4*)&WtP[(size_t)blockIdx.x * TW + (size_t)n * 32 + el] = v;
}

// ---------------------------------------------------------------------------
// K3/K4: f16 MFMA GEMM — R17 measured-best structure (3-deep counted-vmcnt
// pipeline, 64M x 64N, BK=64, grid 1176, XCD swizzle, T2 bank swizzle).
// GELU=true: scales acc by invv[m] (deferred row L2-norm), bias, exact
// GELU, writes packed+swizzled f16.  GELU=false: bias only, f16 row-major.
// ---------------------------------------------------------------------------
template <bool GELU>
__global__ __launch_bounds__(256) void k_mfma_gemm(
    const _Float16* __restrict__ TokP,  // packed (24 x M6 x 32)  B-operand
    const _Float16* __restrict__ WtP,   // packed (24 x 768 x 32) A-operand
    const float* __restrict__ bias,     // (N)
    const float* __restrict__ invv,     // (M6) or nullptr
    _Float16* __restrict__ Cout) {      // packed f16 (GELU) or f16 row-major
    __shared__ _Float16 lA[3][2][64][32];  // [buf][kb][n][k'']
    __shared__ _Float16 lB[3][2][64][32];  // [buf][kb][m][k'']
    const int tid = threadIdx.x;
    const int w = tid >> 6, l = tid & 63;
    const int l15 = l & 15, lk = l >> 4;

    // XCD swizzle: equal lid%8 (one XCD) covers one m-row's 12 n-tiles.
    const int lid = blockIdx.x;
    int vm, vn;
    if (lid < 1152) { vm = (lid / 96) * 8 + (lid & 7); vn = (lid % 96) >> 3; }
    else            { const int r = lid - 1152; vm = 96 + r / 12; vn = r % 12; }
    const int m0 = vm * 64, n0 = vn * 64;
    const int wn = (w & 1) * 32, wm = (w >> 1) * 32;

    f32x4 acc[2][2] = {};   // [fa over n][fb over m]

    // wave w stages one 4 KB chunk per stage: w<2 -> A (kb = w&1), else B
    const int kbsel = w & 1;
    const bool isB = (w >= 2);
    const _Float16* srcBase =
        isB ? (TokP + (size_t)m0 * 32) : (WtP + (size_t)n0 * 32);
    const size_t tileStride = isB ? (size_t)TM : (size_t)TW;
    _Float16* dst0 = isB ? &lB[0][kbsel][0][0] : &lA[0][kbsel][0][0];

#define ISSUE(tt, bf_)                                                         \
    {   const _Float16* s_ = srcBase + (size_t)(2 * (tt) + kbsel) * tileStride;\
        _Float16* d_ = dst0 + (size_t)(bf_) * 4096;                            \
        GLOAD_LDS16(s_ + l * 8,        d_ + l * 8);                            \
        GLOAD_LDS16(s_ + 512 + l * 8,  d_ + 512 + l * 8);                      \
        GLOAD_LDS16(s_ + 1024 + l * 8, d_ + 1024 + l * 8);                     \
        GLOAD_LDS16(s_ + 1536 + l * 8, d_ + 1536 + l * 8); }

    ISSUE(0, 0); ISSUE(1, 1); ISSUE(2, 2);   // 12 loads in flight / wave

    for (int t = 0; t < NT; ++t) {
        // own-wave tile-t loads complete; t+1, t+2 remain in flight
        if (t < NT - 2)       asm volatile("s_waitcnt vmcnt(8)" ::: "memory");
        else if (t == NT - 2) asm volatile("s_waitcnt vmcnt(4)" ::: "memory");
        else                  asm volatile("s_waitcnt vmcnt(0)" ::: "memory");
        __builtin_amdgcn_s_barrier();          // all waves' tile-t loads done
        __builtin_amdgcn_sched_barrier(0);     // no ds_read hoisted above

        const int buf = t % 3;
#pragma unroll
        for (int kk = 0; kk < 2; ++kk) {       // two 32-k sub-steps (kb tiles)
            half8 af[2], bf[2];
#pragma unroll
            for (int fa = 0; fa < 2; ++fa) {
                const int rowA = wn + fa * 16 + l15;
                const int colA = (lk ^ ((rowA >> 1) & 3)) * 8;   // T2 read
                af[fa] = *(const half8*)&lA[buf][kk][rowA][colA];
            }
#pragma unroll
            for (int fb = 0; fb < 2; ++fb) {
                const int rowB = wm + fb * 16 + l15;
                const int colB = (lk ^ ((rowB >> 1) & 3)) * 8;   // T2 read
                bf[fb] = *(const half8*)&lB[buf][kk][rowB][colB];
            }
#pragma unroll
            for (int fa = 0; fa < 2; ++fa)
#pragma unroll
                for (int fb = 0; fb < 2; ++fb)
                    acc[fa][fb] = __builtin_amdgcn_mfma_f32_16x16x32_f16(
                        af[fa], bf[fb], acc[fa][fb], 0, 0, 0);
        }
        asm volatile("s_waitcnt lgkmcnt(0)" ::: "memory");  // reads retired
        __builtin_amdgcn_s_barrier();          // safe to overwrite buf
        __builtin_amdgcn_sched_barrier(0);
        if (t < NT - 3) ISSUE(t + 3, buf);     // refill; stays in flight
    }
#undef ISSUE

    // epilogue: lane holds D[n = nb + r][m], r=0..3 consecutive n
    float invm[2];
    if (GELU) {
#pragma unroll
        for (int fb = 0; fb < 2; ++fb)
            invm[fb] = invv[m0 + wm + fb * 16 + l15];
    }
#pragma unroll
    for (int fa = 0; fa < 2; ++fa) {
        const int nb = n0 + wn + fa * 16 + lk * 4;
        const float4 bv = *(const float4*)&bias[nb];
#pragma unroll
        for (int fb = 0; fb < 2; ++fb) {
            const int m = m0 + wm + fb * 16 + l15;
            half4 o;
            if (GELU) {
#pragma unroll
                for (int rr = 0; rr < 4; ++rr) {
                    float v = acc[fa][fb][rr] * invm[fb] + ((const float*)&bv)[rr];
                    v = 0.5f * v * (1.0f + erff(v * 0.70710678118654752f));
                    o[rr] = (_Float16)v;
                }
                // packed+swizzled write: hdnP[kb][m][ (nb&31)^((m>>1&3)<<3) ]
                const int el = (nb & 31) ^ (((m >> 1) & 3) << 3);
                *(half4*)&Cout[(size_t)(nb >> 5) * TM + (size_t)m * 32 + el] = o;
            } else {
#pragma unroll
                for (int rr = 0; rr < 4; ++rr)
                    o[rr] = (_Float16)(acc[fa][fb][rr] + ((const float*)&bv)[rr]);
                *(half4*)&Cout[(size_t)m * C + nb] = o;   // f16 row-major
            }
        }
    }
}

// ---------------------------------------------------------------------------
// K5: GeM over tokens (f16 input): g[b,c] = (mean_p clip(x,1e-6)^3)^(1/3)
// ---------------------------------------------------------------------------
__global__ __launch_bounds__(256) void k_gempool(const _Float16* __restrict__ tk,
                                                 float* __restrict__ g) {
    const int b = blockIdx.x / 12;
    const int c0 = (blockIdx.x % 12) * 64;
    const int tid = threadIdx.x;
    const int cc = tid & 63, pg = tid >> 6;
    float s = 0.0f;
    for (int p = pg * 49; p < pg * 49 + 49; ++p) {
        const float v = fmaxf((float)tk[((size_t)b * P + p) * C + c0 + cc], 1e-6f);
        s += v * v * v;
    }
    __shared__ float part[4][64];
    part[pg][cc] = s;
    __syncthreads();
    if (tid < 64) {
        const float t4 = part[0][cc] + part[1][cc] + part[2][cc] + part[3][cc];
        g[b * C + c0 + cc] = cbrtf(t4 * (1.0f / (float)P));
    }
}

// ---------------------------------------------------------------------------
// K6a: head GEMM stage 1 (split-K).  grid (NC/64, KSPLIT) = 1536 blocks.
// ---------------------------------------------------------------------------
__global__ __launch_bounds__(256) void k_head1(const float* __restrict__ g,
                                               const float* __restrict__ W,
                                               float* __restrict__ partial) {
    const int n0 = blockIdx.x * 64;
    const int k0 = blockIdx.y * 32;
    __shared__ float gs[32][32];          // [b][kk]
    __shared__ float part[4][32][64];     // [q][b][c]
    const int tid = threadIdx.x;

    for (int idx = tid; idx < 32 * 32; idx += 256)
        gs[idx >> 5][idx & 31] = g[(idx >> 5) * C + k0 + (idx & 31)];
    __syncthreads();

    const int c = tid & 63, q = tid >> 6;
    float acc[32] = {};
#pragma unroll
    for (int kk = 0; kk < 8; ++kk) {
        const int k = q * 8 + kk;
        const float wv = W[(size_t)(k0 + k) * NC + n0 + c];
#pragma unroll
        for (int b = 0; b < 32; ++b) acc[b] += gs[b][k] * wv;
    }
#pragma unroll
    for (int b = 0; b < 32; ++b) part[q][b][c] = acc[b];
    __syncthreads();

    for (int o = tid; o < 32 * 64; o += 256) {
        const int b = o >> 6, cc = o & 63;
        const float v = part[0][b][cc] + part[1][b][cc] +
                        part[2][b][cc] + part[3][b][cc];
        partial[((size_t)blockIdx.y * 32 + b) * NC + n0 + cc] = v;
    }
}

// ---------------------------------------------------------------------------
// K6b: head GEMM stage 2: fixed-order sum of KSPLIT partials + bias.
// ---------------------------------------------------------------------------
__global__ __launch_bounds__(256) void k_head2(const float* __restrict__ partial,
                                               const float* __restrict__ hb,
                                               float* __restrict__ out) {
    const int n = blockIdx.x * 256 + threadIdx.x;
    const int b = blockIdx.y;
    float s = hb[n];
#pragma unroll
    for (int ks = 0; ks < KSPLIT; ++ks)
        s += partial[((size_t)ks * 32 + b) * NC + n];
    out[(size_t)b * NC + n] = s;
}

// ---------------------------------------------------------------------------
// K7: L2-normalize each batch row of out (4096) in place.
// ---------------------------------------------------------------------------
__global__ __launch_bounds__(256) void k_outnorm(float* __restrict__ out) {
    const int b = blockIdx.x;
    float* r = out + (size_t)b * NC;
    const int tid = threadIdx.x;
    float v[16];
    float s = 0.0f;
#pragma unroll
    for (int q = 0; q < 16; ++q) {
        v[q] = r[tid + q * 256];
        s += v[q] * v[q];
    }
    __shared__ float partial[4];
    __shared__ float inv;
#pragma unroll
    for (int off = 32; off > 0; off >>= 1) s += __shfl_xor(s, off);
    if ((tid & 63) == 0) partial[tid >> 6] = s;
    __syncthreads();
    if (tid == 0)
        inv = 1.0f / fmaxf(sqrtf(partial[0] + partial[1] + partial[2] + partial[3]), 1e-12f);
    __syncthreads();
#pragma unroll
    for (int q = 0; q < 16; ++q) r[tid + q * 256] = v[q] * inv;
}

// ---------------------------------------------------------------------------
extern "C" void kernel_launch(void* const* d_in, const int* in_sizes, int n_in,
                              void* d_out, int out_size, void* d_ws, size_t ws_size,
                              hipStream_t stream) {
    const float* patch  = (const float*)d_in[0];
    const float* fc1_w  = (const float*)d_in[1];
    const float* fc1_b  = (const float*)d_in[2];
    const float* fc2_w  = (const float*)d_in[3];
    const float* fc2_b  = (const float*)d_in[4];
    const float* head_w = (const float*)d_in[5];
    const float* head_b = (const float*)d_in[6];
    float* out = (float*)d_out;

    const size_t big = (size_t)B * P * C;        // 4,816,896 elements
    _Float16* tokU  = (_Float16*)d_ws;           // [big] f16 packed+swz (unnorm)
    _Float16* hdnP  = tokU + big;                // [big] f16 packed+swz
    _Float16* wt1   = hdnP + big;                // [768*768] f16 packed+swz
    _Float16* wt2   = wt1 + C * C;               // [768*768] f16 packed+swz
    float*    spart = (float*)(wt2 + C * C);     // [48*M6] row-sumsq partials
    float*    invv  = spart + 48 * (size_t)M6;   // [M6]
    float*    gbuf  = invv + M6;                 // [32*768] f32
    float*    hpart = gbuf + B * C;              // [KSPLIT*32*4096] f32
    _Float16* tok2  = (_Float16*)(hpart + (size_t)KSPLIT * 32 * NC);  // [big]

    // K1: SSA + fusion + residual -> tokU (packed f16) + spart
    k_ssa<<<dim3(48, B), dim3(256), 0, stream>>>(patch, tokU, spart);
    // K1b: row inverse norms
    k_inv<<<dim3((M6 + 255) / 256), dim3(256), 0, stream>>>(spart, invv);
    // weight packs (one launch, z selects matrix)
    k_wt<<<dim3(C / 32, C / 32, 2), dim3(256), 0, stream>>>(
        fc1_w, fc2_w, wt1, wt2);
    // K3: fc1 (deferred norm via invv) + gelu -> hdnP (f16 packed+swz)
    k_mfma_gemm<true><<<dim3(1176), dim3(256), 0, stream>>>(
        tokU, wt1, fc1_b, invv, hdnP);
    // K4: fc2 -> tok2 (f16 row-major)
    k_mfma_gemm<false><<<dim3(1176), dim3(256), 0, stream>>>(
        hdnP, wt2, fc2_b, nullptr, tok2);
    // K5: GeM over tokens -> gbuf
    k_gempool<<<dim3(B * 12), dim3(256), 0, stream>>>(tok2, gbuf);
    // K6: head GEMM, split-K two-stage -> out (pre-normalized)
    k_head1<<<dim3(NC / 64, KSPLIT), dim3(256), 0, stream>>>(gbuf, head_w, hpart);
    k_head2<<<dim3(NC / 256, B), dim3(256), 0, stream>>>(hpart, head_b, out);
    // K7: normalize rows of out
    k_outnorm<<<dim3(B), dim3(256), 0, stream>>>(out);
}

// Round 19
// 82.594 us; speedup vs baseline: 1.1818x; 1.1297x over previous
//
#include <hip/hip_runtime.h>
#include <hip/hip_bf16.h>
#include <math.h>

// Problem dims (fixed by reference)
#define B   32
#define P   196      // hw tokens (14x14)
#define C   768
#define NC  4096
#define HH  14
#define KSPLIT 12    // 768 / 64
#define NT  12       // K tiles per GEMM (768 / 64)
#define M6  6272     // B*P
// Packed k-tiled layout with T2 bank swizzle (R17, measured-best):
//   element (row, k) stored at X[kb][row][ k' ^ (((row>>1)&3)<<3) ]
//   (kb = k>>5, k' = k&31).  Staging is a LINEAR 4 KB copy; LDS fragment
//   reads apply the same XOR -> 2-way bank conflict (free).
#define TW  (768 * 32)    // Wt packed kb stride (elements)
#define TM  (M6 * 32)     // Tok/hdn packed kb stride (elements)

typedef _Float16 half8 __attribute__((ext_vector_type(8)));
typedef _Float16 half4 __attribute__((ext_vector_type(4)));
typedef float f32x4 __attribute__((ext_vector_type(4)));

#define GLOAD_LDS16(g, l)                                                      \
    __builtin_amdgcn_global_load_lds(                                          \
        (const __attribute__((address_space(1))) void*)(g),                    \
        (__attribute__((address_space(3))) void*)(l), 16, 0, 0)

// ---------------------------------------------------------------------------
// K1: SpaceSelfAware + space_fusion + residual + PACK (R18 version).
// ---------------------------------------------------------------------------
__global__ __launch_bounds__(256) void k_ssa(const float* __restrict__ t,
                                             _Float16* __restrict__ outP,
                                             float* __restrict__ partial) {
    const int b = blockIdx.y, cb = blockIdx.x, c0 = cb * 16;
    __shared__ float xp_[256 * 16];        // [(i+2)*16 + (j+1)][cc]  16 KB
    __shared__ float part[4][9][16];
    __shared__ float inv_norm[9][16];
    __shared__ _Float16 outT[P][16];       // 6.3 KB
    const int tid = threadIdx.x;
    const int cc = tid & 15, g = tid >> 4, wv = tid >> 6;

#pragma unroll
    for (int q = 0; q < 16; ++q) xp_[q * 256 + tid] = 0.0f;
    __syncthreads();

    for (int idx = tid; idx < 784; idx += 256) {
        const int p = idx >> 2, c = (idx & 3) * 4;
        const int i = p / HH, j = p % HH;
        *(float4*)&xp_[((i + 2) * 16 + (j + 1)) * 16 + c] =
            *(const float4*)&t[((size_t)b * P + p) * C + c0 + c];
    }
    __syncthreads();

    float s[9] = {};
    {
        int i = 0, j = g;
        if (j >= HH) { j -= HH; i = 1; }
        for (int p = g; p < P; p += 16) {
            const int base = ((i + 2) * 16 + (j + 1)) * 16 + cc;
            const float xp = xp_[base];
            const float xp2 = xp * xp;
#pragma unroll
            for (int k = 0; k < 9; ++k) {
                const int off = ((k / 3) - 2) * 16 + (k % 3) - 1;  // const
                const float nb = xp_[base + off * 16];
                s[k] += xp2 * nb * nb;
            }
            j += 2; ++i;
            if (j >= HH) { j -= HH; ++i; }
        }
    }
#pragma unroll
    for (int k = 0; k < 9; ++k) {
        float r = s[k];
        r += __shfl_xor(r, 16);
        r += __shfl_xor(r, 32);
        s[k] = r;
    }
    if ((tid & 63) < 16) {
#pragma unroll
        for (int k = 0; k < 9; ++k) part[wv][k][cc] = s[k];
    }
    __syncthreads();
    if (tid < 144) {
        const int k = tid >> 4, c2 = tid & 15;
        const float t4 = part[0][k][c2] + part[1][k][c2] +
                         part[2][k][c2] + part[3][k][c2];
        inv_norm[k][c2] = 1.0f / fmaxf(sqrtf(t4), 1e-12f);
    }
    __syncthreads();

    float invn[9];
#pragma unroll
    for (int k = 0; k < 9; ++k) invn[k] = inv_norm[k][cc];

    {
        int i = 0, j = g;
        if (j >= HH) { j -= HH; i = 1; }
        for (int p = g; p < P; p += 16) {
            const int base = ((i + 2) * 16 + (j + 1)) * 16 + cc;
            const float xp = xp_[base];
            float acc = 0.0f;
#pragma unroll
            for (int k = 0; k < 9; ++k) {
                const int off = ((k / 3) - 2) * 16 + (k % 3) - 1;
                const float v = xp * xp_[base + off * 16];
                const float u = fmaxf(v * invn[k], 1e-6f);
                acc += u * u * u;
            }
            const float val = cbrtf(acc * (1.0f / 9.0f)) + xp;
            float rs = val * val;
            rs += __shfl_xor(rs, 1);
            rs += __shfl_xor(rs, 2);
            rs += __shfl_xor(rs, 4);
            rs += __shfl_xor(rs, 8);
            outT[p][cc] = (_Float16)val;
            if (cc == 0) partial[(size_t)cb * M6 + b * P + p] = rs;
            j += 2; ++i;
            if (j >= HH) { j -= HH; ++i; }
        }
    }
    __syncthreads();
    // pack: 392 half8 stores into tokU[kb][row][swizzled slot]
    const int kb = cb >> 1, kbase = (cb & 1) * 16;
    for (int idx = tid; idx < P * 2; idx += 256) {
        const int p = idx >> 1, h = idx & 1;
        const half8 v = *(const half8*)&outT[p][h * 8];
        const int row = b * P + p;
        const int slot = ((kbase + h * 8) >> 3) ^ ((row >> 1) & 3);   // T2
        *(half8*)&outP[(size_t)kb * TM + (size_t)row * 32 + slot * 8] = v;
    }
}

// ---------------------------------------------------------------------------
// K2: merged prep — z<2: weight pack (W -> packed+swizzled f16); z==2:
// inv[row] = 1/max(sqrt(sum of 48 ssa partials), eps).
// ---------------------------------------------------------------------------
__global__ __launch_bounds__(256) void k_prep(const float* __restrict__ W1,
                                              const float* __restrict__ W2,
                                              _Float16* __restrict__ O1,
                                              _Float16* __restrict__ O2,
                                              const float* __restrict__ spart,
                                              float* __restrict__ invv) {
    if (blockIdx.z == 2) {
        const int row = (blockIdx.y * 24 + blockIdx.x) * 256 + threadIdx.x;
        if (row < M6) {
            float s = 0.0f;
#pragma unroll 8
            for (int cb = 0; cb < 48; ++cb) s += spart[(size_t)cb * M6 + row];
            invv[row] = 1.0f / fmaxf(sqrtf(s), 1e-12f);
        }
        return;
    }
    const float* W = blockIdx.z ? W2 : W1;
    _Float16* WtP = blockIdx.z ? O2 : O1;
    __shared__ float tt[32][33];
    const int k0 = blockIdx.x * 32, n0 = blockIdx.y * 32;   // kb = blockIdx.x
    const int r = threadIdx.x / 32, c = threadIdx.x % 32;
#pragma unroll
    for (int q = 0; q < 4; ++q)
        tt[r + q * 8][c] = W[(size_t)(k0 + r + q * 8) * C + n0 + c];
    __syncthreads();
    const int nl = threadIdx.x >> 3, h = threadIdx.x & 7;
    const int n = n0 + nl;
    half4 v;
#pragma unroll
    for (int j = 0; j < 4; ++j) v[j] = (_Float16)tt[h * 4 + j][nl];
    const int el = (h * 4) ^ (((n >> 1) & 3) << 3);          // T2 swizzle
    *(half4*)&WtP[(size_t)blockIdx.x * TW + (size_t)n * 32 + el] = v;
}

// ---------------------------------------------------------------------------
// K3/K4: f16 MFMA GEMM — R17 measured-best structure (3-deep counted-vmcnt
// pipeline, 64M x 64N, BK=64, grid 1176, XCD swizzle, T2 bank swizzle).
// GELU=true (fc1): acc*invv[m] (deferred row norm) + bias + exact GELU,
// writes packed+swizzled f16.
// GELU=false (fc2): acc + bias, then FUSED GeM partials: per-block 64-row
// sums of clip(v,1e-6)^3 per column, split by batch segment (a 64-row block
// spans <=2 batches; always exactly 4 vm blocks per batch since
// 196 mod 64 = 4), written to gpart[b][vmLocal][n].  No token output.
// ---------------------------------------------------------------------------
template <bool GELU>
__global__ __launch_bounds__(256) void k_mfma_gemm(
    const _Float16* __restrict__ TokP,  // packed (24 x M6 x 32)  B-operand
    const _Float16* __restrict__ WtP,   // packed (24 x 768 x 32) A-operand
    const float* __restrict__ bias,     // (N)
    const float* __restrict__ invv,     // (M6) or nullptr
    _Float16* __restrict__ Cout,        // packed f16 (GELU) or unused
    float* __restrict__ gpart) {        // (32 x 4 x 768) (fc2) or unused
    __shared__ _Float16 lA[3][2][64][32];  // [buf][kb][n][k'']
    __shared__ _Float16 lB[3][2][64][32];  // [buf][kb][m][k'']
    __shared__ float part2[2][2][64];      // [wmhalf][seg][n]  (fc2 only)
    const int tid = threadIdx.x;
    const int w = tid >> 6, l = tid & 63;
    const int l15 = l & 15, lk = l >> 4;

    // XCD swizzle: equal lid%8 (one XCD) covers one m-row's 12 n-tiles.
    const int lid = blockIdx.x;
    int vm, vn;
    if (lid < 1152) { vm = (lid / 96) * 8 + (lid & 7); vn = (lid % 96) >> 3; }
    else            { const int r = lid - 1152; vm = 96 + r / 12; vn = r % 12; }
    const int m0 = vm * 64, n0 = vn * 64;
    const int wn = (w & 1) * 32, wm = (w >> 1) * 32;

    f32x4 acc[2][2] = {};   // [fa over n][fb over m]

    // wave w stages one 4 KB chunk per stage: w<2 -> A (kb = w&1), else B
    const int kbsel = w & 1;
    const bool isB = (w >= 2);
    const _Float16* srcBase =
        isB ? (TokP + (size_t)m0 * 32) : (WtP + (size_t)n0 * 32);
    const size_t tileStride = isB ? (size_t)TM : (size_t)TW;
    _Float16* dst0 = isB ? &lB[0][kbsel][0][0] : &lA[0][kbsel][0][0];

#define ISSUE(tt, bf_)                                                         \
    {   const _Float16* s_ = srcBase + (size_t)(2 * (tt) + kbsel) * tileStride;\
        _Float16* d_ = dst0 + (size_t)(bf_) * 4096;                            \
        GLOAD_LDS16(s_ + l * 8,        d_ + l * 8);                            \
        GLOAD_LDS16(s_ + 512 + l * 8,  d_ + 512 + l * 8);                      \
        GLOAD_LDS16(s_ + 1024 + l * 8, d_ + 1024 + l * 8);                     \
        GLOAD_LDS16(s_ + 1536 + l * 8, d_ + 1536 + l * 8); }

    ISSUE(0, 0); ISSUE(1, 1); ISSUE(2, 2);   // 12 loads in flight / wave

    for (int t = 0; t < NT; ++t) {
        // own-wave tile-t loads complete; t+1, t+2 remain in flight
        if (t < NT - 2)       asm volatile("s_waitcnt vmcnt(8)" ::: "memory");
        else if (t == NT - 2) asm volatile("s_waitcnt vmcnt(4)" ::: "memory");
        else                  asm volatile("s_waitcnt vmcnt(0)" ::: "memory");
        __builtin_amdgcn_s_barrier();          // all waves' tile-t loads done
        __builtin_amdgcn_sched_barrier(0);     // no ds_read hoisted above

        const int buf = t % 3;
#pragma unroll
        for (int kk = 0; kk < 2; ++kk) {       // two 32-k sub-steps (kb tiles)
            half8 af[2], bf[2];
#pragma unroll
            for (int fa = 0; fa < 2; ++fa) {
                const int rowA = wn + fa * 16 + l15;
                const int colA = (lk ^ ((rowA >> 1) & 3)) * 8;   // T2 read
                af[fa] = *(const half8*)&lA[buf][kk][rowA][colA];
            }
#pragma unroll
            for (int fb = 0; fb < 2; ++fb) {
                const int rowB = wm + fb * 16 + l15;
                const int colB = (lk ^ ((rowB >> 1) & 3)) * 8;   // T2 read
                bf[fb] = *(const half8*)&lB[buf][kk][rowB][colB];
            }
#pragma unroll
            for (int fa = 0; fa < 2; ++fa)
#pragma unroll
                for (int fb = 0; fb < 2; ++fb)
                    acc[fa][fb] = __builtin_amdgcn_mfma_f32_16x16x32_f16(
                        af[fa], bf[fb], acc[fa][fb], 0, 0, 0);
        }
        asm volatile("s_waitcnt lgkmcnt(0)" ::: "memory");  // reads retired
        __builtin_amdgcn_s_barrier();          // safe to overwrite buf
        __builtin_amdgcn_sched_barrier(0);
        if (t < NT - 3) ISSUE(t + 3, buf);     // refill; stays in flight
    }
#undef ISSUE

    // epilogue: lane holds D[n = nb + r][m], r=0..3 consecutive n
    const int b0 = m0 / P;
    const int rsplit = (b0 + 1) * P;
    float invm[2];
    if constexpr (GELU) {
#pragma unroll
        for (int fb = 0; fb < 2; ++fb)
            invm[fb] = invv[m0 + wm + fb * 16 + l15];
    }
#pragma unroll
    for (int fa = 0; fa < 2; ++fa) {
        const int nb = n0 + wn + fa * 16 + lk * 4;
        const float4 bv = *(const float4*)&bias[nb];
        if constexpr (GELU) {
#pragma unroll
            for (int fb = 0; fb < 2; ++fb) {
                const int m = m0 + wm + fb * 16 + l15;
                half4 o;
#pragma unroll
                for (int rr = 0; rr < 4; ++rr) {
                    float v = acc[fa][fb][rr] * invm[fb] + ((const float*)&bv)[rr];
                    v = 0.5f * v * (1.0f + erff(v * 0.70710678118654752f));
                    o[rr] = (_Float16)v;
                }
                const int el = (nb & 31) ^ (((m >> 1) & 3) << 3);
                *(half4*)&Cout[(size_t)(nb >> 5) * TM + (size_t)m * 32 + el] = o;
            }
        } else {
#pragma unroll
            for (int rr = 0; rr < 4; ++rr) {
                float s0 = 0.0f, s1 = 0.0f;
#pragma unroll
                for (int fb = 0; fb < 2; ++fb) {
                    const int m = m0 + wm + fb * 16 + l15;
                    const float v = acc[fa][fb][rr] + ((const float*)&bv)[rr];
                    const float u = fmaxf(v, 1e-6f);
                    const float u3 = u * u * u;
                    if (m >= rsplit) s1 += u3; else s0 += u3;
                }
                s0 += __shfl_xor(s0, 1); s0 += __shfl_xor(s0, 2);
                s0 += __shfl_xor(s0, 4); s0 += __shfl_xor(s0, 8);
                s1 += __shfl_xor(s1, 1); s1 += __shfl_xor(s1, 2);
                s1 += __shfl_xor(s1, 4); s1 += __shfl_xor(s1, 8);
                if (l15 == 0) {
                    part2[w >> 1][0][wn + fa * 16 + lk * 4 + rr] = s0;
                    part2[w >> 1][1][wn + fa * 16 + lk * 4 + rr] = s1;
                }
            }
        }
    }
    if constexpr (!GELU) {
        __syncthreads();
        if (tid < 128) {
            const int seg = tid >> 6, nn = tid & 63;
            const float tot = part2[0][seg][nn] + part2[1][seg][nn];
            if (seg == 0) {
                const int q = vm - ((b0 * 49) >> 4);   // vm - first_vm(b0)
                gpart[((size_t)b0 * 4 + q) * C + n0 + nn] = tot;
            } else if (rsplit < m0 + 64) {             // straddling block
                gpart[((size_t)(b0 + 1) * 4 + 0) * C + n0 + nn] = tot;
            }
        }
    }
}

// ---------------------------------------------------------------------------
// K5: final GeM combine: g[b,c] = cbrt(mean of 4 fixed-order partials).
// ---------------------------------------------------------------------------
__global__ __launch_bounds__(256) void k_gempool2(const float* __restrict__ gpart,
                                                  float* __restrict__ g) {
    const int b = blockIdx.x / 3;
    const int c = (blockIdx.x % 3) * 256 + threadIdx.x;
    const float s = gpart[((size_t)b * 4 + 0) * C + c] +
                    gpart[((size_t)b * 4 + 1) * C + c] +
                    gpart[((size_t)b * 4 + 2) * C + c] +
                    gpart[((size_t)b * 4 + 3) * C + c];
    g[b * C + c] = cbrtf(s * (1.0f / (float)P));
}

// ---------------------------------------------------------------------------
// K6a: head GEMM stage 1 (split-K, 64 k per block).  grid (64, 12).
// ---------------------------------------------------------------------------
__global__ __launch_bounds__(256) void k_head1(const float* __restrict__ g,
                                               const float* __restrict__ W,
                                               float* __restrict__ partial) {
    const int n0 = blockIdx.x * 64;
    const int k0 = blockIdx.y * 64;
    __shared__ float gs[32][64];          // [b][kk]  8 KB
    __shared__ float part[4][32][64];     // [q][b][c] 32 KB
    const int tid = threadIdx.x;

    for (int idx = tid; idx < 32 * 64; idx += 256)
        gs[idx >> 6][idx & 63] = g[(idx >> 6) * C + k0 + (idx & 63)];
    __syncthreads();

    const int c = tid & 63, q = tid >> 6;
    float acc[32] = {};
#pragma unroll
    for (int kk = 0; kk < 16; ++kk) {
        const int k = q * 16 + kk;
        const float wv = W[(size_t)(k0 + k) * NC + n0 + c];
#pragma unroll
        for (int b = 0; b < 32; ++b) acc[b] += gs[b][k] * wv;
    }
#pragma unroll
    for (int b = 0; b < 32; ++b) part[q][b][c] = acc[b];
    __syncthreads();

    for (int o = tid; o < 32 * 64; o += 256) {
        const int b = o >> 6, cc = o & 63;
        const float v = part[0][b][cc] + part[1][b][cc] +
                        part[2][b][cc] + part[3][b][cc];
        partial[((size_t)blockIdx.y * 32 + b) * NC + n0 + cc] = v;
    }
}

// ---------------------------------------------------------------------------
// K6b: head GEMM stage 2: fixed-order sum of KSPLIT partials + bias.
// ---------------------------------------------------------------------------
__global__ __launch_bounds__(256) void k_head2(const float* __restrict__ partial,
                                               const float* __restrict__ hb,
                                               float* __restrict__ out) {
    const int n = blockIdx.x * 256 + threadIdx.x;
    const int b = blockIdx.y;
    float s = hb[n];
#pragma unroll
    for (int ks = 0; ks < KSPLIT; ++ks)
        s += partial[((size_t)ks * 32 + b) * NC + n];
    out[(size_t)b * NC + n] = s;
}

// ---------------------------------------------------------------------------
// K7: L2-normalize each batch row of out (4096) in place.
// ---------------------------------------------------------------------------
__global__ __launch_bounds__(256) void k_outnorm(float* __restrict__ out) {
    const int b = blockIdx.x;
    float* r = out + (size_t)b * NC;
    const int tid = threadIdx.x;
    float v[16];
    float s = 0.0f;
#pragma unroll
    for (int q = 0; q < 16; ++q) {
        v[q] = r[tid + q * 256];
        s += v[q] * v[q];
    }
    __shared__ float partial[4];
    __shared__ float inv;
#pragma unroll
    for (int off = 32; off > 0; off >>= 1) s += __shfl_xor(s, off);
    if ((tid & 63) == 0) partial[tid >> 6] = s;
    __syncthreads();
    if (tid == 0)
        inv = 1.0f / fmaxf(sqrtf(partial[0] + partial[1] + partial[2] + partial[3]), 1e-12f);
    __syncthreads();
#pragma unroll
    for (int q = 0; q < 16; ++q) r[tid + q * 256] = v[q] * inv;
}

// ---------------------------------------------------------------------------
extern "C" void kernel_launch(void* const* d_in, const int* in_sizes, int n_in,
                              void* d_out, int out_size, void* d_ws, size_t ws_size,
                              hipStream_t stream) {
    const float* patch  = (const float*)d_in[0];
    const float* fc1_w  = (const float*)d_in[1];
    const float* fc1_b  = (const float*)d_in[2];
    const float* fc2_w  = (const float*)d_in[3];
    const float* fc2_b  = (const float*)d_in[4];
    const float* head_w = (const float*)d_in[5];
    const float* head_b = (const float*)d_in[6];
    float* out = (float*)d_out;

    const size_t big = (size_t)B * P * C;        // 4,816,896 elements
    _Float16* tokU  = (_Float16*)d_ws;           // [big] f16 packed+swz (unnorm)
    _Float16* hdnP  = tokU + big;                // [big] f16 packed+swz
    _Float16* wt1   = hdnP + big;                // [768*768] f16 packed+swz
    _Float16* wt2   = wt1 + C * C;               // [768*768] f16 packed+swz
    float*    spart = (float*)(wt2 + C * C);     // [48*M6] row-sumsq partials
    float*    invv  = spart + 48 * (size_t)M6;   // [M6]
    float*    gbuf  = invv + M6;                 // [32*768] f32
    float*    gpart = gbuf + B * C;              // [32*4*768] f32
    float*    hpart = gpart + (size_t)B * 4 * C; // [KSPLIT*32*4096] f32

    // K1: SSA + fusion + residual -> tokU (packed f16) + spart
    k_ssa<<<dim3(48, B), dim3(256), 0, stream>>>(patch, tokU, spart);
    // K2: weight packs (z<2) + row inverse norms (z==2)
    k_prep<<<dim3(C / 32, C / 32, 3), dim3(256), 0, stream>>>(
        fc1_w, fc2_w, wt1, wt2, spart, invv);
    // K3: fc1 (deferred norm via invv) + gelu -> hdnP (f16 packed+swz)
    k_mfma_gemm<true><<<dim3(1176), dim3(256), 0, stream>>>(
        tokU, wt1, fc1_b, invv, hdnP, nullptr);
    // K4: fc2 + fused GeM partials -> gpart (no token output)
    k_mfma_gemm<false><<<dim3(1176), dim3(256), 0, stream>>>(
        hdnP, wt2, fc2_b, nullptr, nullptr, gpart);
    // K5: GeM combine -> gbuf
    k_gempool2<<<dim3(B * 3), dim3(256), 0, stream>>>(gpart, gbuf);
    // K6: head GEMM, split-K two-stage -> out (pre-normalized)
    k_head1<<<dim3(NC / 64, KSPLIT), dim3(256), 0, stream>>>(gbuf, head_w, hpart);
    k_head2<<<dim3(NC / 256, B), dim3(256), 0, stream>>>(hpart, head_b, out);
    // K7: normalize rows of out
    k_outnorm<<<dim3(B), dim3(256), 0, stream>>>(out);
}